// Round 9
// baseline (408.393 us; speedup 1.0000x reference)
//
#include <hip/hip_runtime.h>

// Transformer block on MI355X. bf16 MFMA for GEMMs/QK^T, fp16 MFMA for PV, fp32 stats.
// GEMM: C[M,N] = A[M,K] (row-major bf16) x Bt[N,K] (row-major bf16 = B^T).
// MFMA 16x16x32 bf16 frags: A/B [idx=lane&15][k=quad*8+j]; C/D col=lane&15, row=quad*4+reg.
// MFMA 16x16x16 f16 frags:  A/B [idx=lane&15][k=quad*4+j]; C/D same 16x16 layout.
// Attention v8: barrier-free, LDS-free. Each wave streams K/V fragments directly
// global->VGPR (K double-buffered in registers, V per-iter), no __syncthreads at all.
// bh = blockIdx&31 and 32%8==0 keeps each XCD on 4 (b,h) pairs -> K/V L2-resident.
// l accumulated via MFMA against a ones-fragment (no VALU adds, no epilogue shuffles).

typedef unsigned short u16;
typedef unsigned int u32;
typedef __attribute__((ext_vector_type(8))) short bf16x8;
typedef __attribute__((ext_vector_type(4))) float f32x4;
typedef __attribute__((ext_vector_type(2))) u32 u32x2;
typedef __attribute__((ext_vector_type(4))) _Float16 f16x4;

#define MFMA16(a, b, c) __builtin_amdgcn_mfma_f32_16x16x32_bf16(a, b, c, 0, 0, 0)
#define MFMAH(a, b, c) __builtin_amdgcn_mfma_f32_16x16x16f16(a, b, c, 0, 0, 0)

__device__ __forceinline__ u16 f2b(float f) {
  unsigned int u = __builtin_bit_cast(unsigned int, f);
  u = (u + 0x7fffu + ((u >> 16) & 1u)) >> 16;
  return (u16)u;
}

__device__ __forceinline__ void gload_lds16(const u16* g, u16* l) {
  __builtin_amdgcn_global_load_lds((const __attribute__((address_space(1))) void*)g,
                                   (__attribute__((address_space(3))) void*)l, 16, 0, 0);
}

__device__ __forceinline__ u32 pkrtz(float lo, float hi) {
  return __builtin_bit_cast(u32, __builtin_amdgcn_cvt_pkrtz(lo, hi));
}

__device__ __forceinline__ f16x4 pack4h(float a, float b, float c, float d) {
  u32x2 r = {pkrtz(a, b), pkrtz(c, d)};
  return __builtin_bit_cast(f16x4, r);
}

__device__ __forceinline__ u16 f2h(float v) {
  return __builtin_bit_cast(u16, (_Float16)v);
}

// ---------------------------------------------------------------- pack kernels

__global__ __launch_bounds__(256) void castx_kernel(const float* __restrict__ src,
                                                    u16* __restrict__ dst) {
  int i = (blockIdx.x * 256 + threadIdx.x) * 4;
  float4 v = *(const float4*)(src + i);
  dst[i + 0] = f2b(v.x);
  dst[i + 1] = f2b(v.y);
  dst[i + 2] = f2b(v.z);
  dst[i + 3] = f2b(v.w);
}

__global__ __launch_bounds__(256) void tcast_kernel(const float* __restrict__ src,
                                                    u16* __restrict__ dst, int R, int C) {
  __shared__ float tile[32][33];
  int tx = threadIdx.x, ty = threadIdx.y;
  int r0 = blockIdx.y * 32, c0 = blockIdx.x * 32;
#pragma unroll
  for (int i = 0; i < 4; ++i)
    tile[ty + i * 8][tx] = src[(size_t)(r0 + ty + i * 8) * C + c0 + tx];
  __syncthreads();
#pragma unroll
  for (int i = 0; i < 4; ++i)
    dst[(size_t)(c0 + ty + i * 8) * R + r0 + tx] = f2b(tile[tx][ty + i * 8]);
}

// per-(proj,head) transpose of [1024 d][64 k] into WqkvT[n=p*1024+h*64+k][d].
// q gets (1/sqrt(64))*log2(e) folded in (attn uses exp2).
__global__ __launch_bounds__(256) void tcast_qkv_kernel(const float* __restrict__ wq,
                                                        const float* __restrict__ wk,
                                                        const float* __restrict__ wv,
                                                        u16* __restrict__ dst) {
  __shared__ float tile[32][33];
  int tx = threadIdx.x, ty = threadIdx.y;
  int z = blockIdx.z;
  int p = z >> 4, h = z & 15;
  const float* src = (p == 0 ? wq : (p == 1 ? wk : wv)) + (size_t)h * 1024 * 64;
  float scale = (p == 0) ? 0.1803368801f : 1.0f;  // 0.125 * log2(e)
  u16* dbase = dst + (size_t)(p * 1024 + h * 64) * 1024;
  int r0 = blockIdx.y * 32, c0 = blockIdx.x * 32;
#pragma unroll
  for (int i = 0; i < 4; ++i)
    tile[ty + i * 8][tx] = src[(size_t)(r0 + ty + i * 8) * 64 + c0 + tx];
  __syncthreads();
#pragma unroll
  for (int i = 0; i < 4; ++i)
    dbase[(size_t)(c0 + ty + i * 8) * 1024 + r0 + tx] = f2b(tile[tx][ty + i * 8] * scale);
}

// ---------------------------------------------------------------- GEMM v3
// BM=128, BN=128, BK=64, grid (Mtiles, Ntiles, KS). k range [z*Kc, (z+1)*Kc).
// LDS staged via global_load_lds with 16B-chunk XOR swizzle (conflict-free reads).
// MODE 1: relu(C+bias) bf16 -> outB (ldc)
// MODE 3: QKV fused: n0<2048 -> bf16 natural (ldc) | n0>=2048 -> V^T f16 to vtg
// MODE 4: f16 partial -> outB + z*M*N (combined later by ln_comb)

template <int MODE>
__global__ __launch_bounds__(256) void gemm_bf16(const u16* __restrict__ A,
                                                 const u16* __restrict__ Bt, int M, int N,
                                                 int Kc, int lda,
                                                 const float* __restrict__ bias,
                                                 u16* __restrict__ outB, int ldc,
                                                 u16* __restrict__ vtg) {
  constexpr int BM = 128, BN = 128, BK = 64;
  constexpr int IM = 4, JN = 4;
  __shared__ u16 As[BM * BK];
  __shared__ u16 Bs[BN * BK];
  int t = threadIdx.x;
  int m0 = blockIdx.x * BM, n0 = blockIdx.y * BN;
  int kb = blockIdx.z * Kc;
  int lane = t & 63, wid = t >> 6;
  int wm = (wid >> 1) * 64, wn = (wid & 1) * 64;
  int m16 = lane & 15, quad = lane >> 4;
  int sw = m16 & 7;

  f32x4 acc[IM][JN] = {};

  for (int k0 = kb; k0 < kb + Kc; k0 += BK) {
    __syncthreads();
#pragma unroll
    for (int i = 0; i < 4; ++i) {
      int S = i * 256 + t;
      int row = S >> 3, c = S & 7;
      gload_lds16(&A[(size_t)(m0 + row) * lda + k0 + (c ^ (row & 7)) * 8],
                  &As[(i * 256 + wid * 64) * 8]);
    }
#pragma unroll
    for (int i = 0; i < 4; ++i) {
      int S = i * 256 + t;
      int row = S >> 3, c = S & 7;
      gload_lds16(&Bt[(size_t)(n0 + row) * lda + k0 + (c ^ (row & 7)) * 8],
                  &Bs[(i * 256 + wid * 64) * 8]);
    }
    __syncthreads();
#pragma unroll
    for (int kk = 0; kk < 2; ++kk) {
      bf16x8 af[IM], bfr[JN];
      int slot = (kk * 4 + quad) ^ sw;
#pragma unroll
      for (int i = 0; i < IM; ++i)
        af[i] = *(const bf16x8*)&As[(wm + i * 16 + m16) * BK + slot * 8];
#pragma unroll
      for (int j = 0; j < JN; ++j)
        bfr[j] = *(const bf16x8*)&Bs[(wn + j * 16 + m16) * BK + slot * 8];
#pragma unroll
      for (int i = 0; i < IM; ++i)
#pragma unroll
        for (int j = 0; j < JN; ++j) acc[i][j] = MFMA16(af[i], bfr[j], acc[i][j]);
    }
  }

  if (MODE == 3 && n0 >= 2048) {
#pragma unroll
    for (int i = 0; i < IM; ++i)
#pragma unroll
      for (int j = 0; j < JN; ++j) {
        int dg = n0 + wn + j * 16 + m16 - 2048;
        int hh = dg >> 6, dd = dg & 63;
        int token = m0 + wm + i * 16 + quad * 4;
        int bb = token >> 11, tt = token & 2047;
        u32x2 pv = {pkrtz(acc[i][j][0], acc[i][j][1]),
                    pkrtz(acc[i][j][2], acc[i][j][3])};
        *(u32x2*)&vtg[(((size_t)bb * 16 + hh) * 64 + dd) * 2048 + tt] = pv;
      }
    return;
  }

  u16* pb = (MODE == 4) ? outB + (size_t)blockIdx.z * M * N : outB;
#pragma unroll
  for (int i = 0; i < IM; ++i)
#pragma unroll
    for (int j = 0; j < JN; ++j) {
      int col = n0 + wn + j * 16 + m16;
      float bv = (MODE == 1) ? bias[col] : 0.0f;
#pragma unroll
      for (int r = 0; r < 4; ++r) {
        int row = m0 + wm + i * 16 + quad * 4 + r;
        float v = acc[i][j][r];
        if (MODE == 1) {
          v += bv;
          v = v > 0.0f ? v : 0.0f;
          pb[(size_t)row * ldc + col] = f2b(v);
        } else if (MODE == 4) {
          pb[(size_t)row * ldc + col] = f2h(v);
        } else {
          pb[(size_t)row * ldc + col] = f2b(v);
        }
      }
    }
}

// ---------------------------------------------------------------- attention v8
// Barrier-free streaming. Same split-K schedule as v7 (32 LPT ranks x 32 bh).
// Each wave: 32 q rows, clamps its own key range (causal), streams K (register
// double-buffer, one tile ahead) and V (issued at iter start) from global.

__constant__ unsigned char R_QB[32] = {7, 6, 11, 11, 5, 10, 10, 9, 9, 4, 8,
                                       8, 3, 15, 15, 15, 15, 14, 14, 14, 13, 13,
                                       13, 13, 12, 12, 12, 2, 14, 12, 1, 0};
__constant__ unsigned char R_K0[32] = {0, 0, 0, 12, 0, 0, 11, 0, 10, 0, 0,
                                       9, 0, 0, 8, 16, 24, 0, 8, 16, 0, 7,
                                       14, 21, 0, 7, 14, 0, 24, 21, 0, 0};
__constant__ unsigned char R_NIT[32] = {16, 14, 12, 12, 12, 11, 11, 10, 10, 10, 9,
                                        9, 8, 8, 8, 8, 8, 8, 8, 8, 7, 7,
                                        7, 7, 7, 7, 7, 6, 6, 5, 4, 2};
__constant__ unsigned char R_ST[32] = {255, 255, 6, 7, 255, 4, 5, 2, 3, 255, 0,
                                       1, 255, 20, 21, 22, 23, 16, 17, 18, 12, 13,
                                       14, 15, 8, 9, 10, 255, 19, 11, 255, 255};
__constant__ unsigned char CB_BASE[8] = {0, 2, 4, 6, 8, 12, 16, 20};

__global__ __launch_bounds__(256) void attn_part(const u16* __restrict__ qk,
                                                 const u16* __restrict__ vtg,
                                                 u16* __restrict__ attn_out,
                                                 u16* __restrict__ opart,
                                                 float2* __restrict__ ml) {
  int rank = blockIdx.x >> 5, bh = blockIdx.x & 31;
  int qb = R_QB[rank];
  int k_start = R_K0[rank] * 64;
  int nit_blk = R_NIT[rank];
  int st = R_ST[rank];
  int b = bh >> 4, h = bh & 15;

  int t = threadIdx.x, lane = t & 63, w = t >> 6;
  int m16 = lane & 15, quad = lane >> 4;
  int wq0 = qb * 128 + w * 32;

  // per-wave causal clamp of the key range (no in-loop skips, no barriers)
  int k_end = min(k_start + nit_blk * 64, wq0 + 32);
  int iters = (k_end - k_start + 63) >> 6;  // >= 1 always (k_start <= qb*128 <= wq0)

  // Q fragments (B-operand of S^T MFMA); scale+log2e folded into wq pack
  bf16x8 qa[2][2];
#pragma unroll
  for (int qs = 0; qs < 2; ++qs) {
    const u16* qp = qk + (size_t)(b * 2048 + wq0 + qs * 16 + m16) * 2048 + h * 64;
    qa[qs][0] = *(const bf16x8*)&qp[quad * 8];
    qa[qs][1] = *(const bf16x8*)&qp[32 + quad * 8];
  }

  // lane base pointers: K frag (ts,half) at kb + (t0+ts*16)*2048 + half*32
  const u16* kb = qk + ((size_t)(b * 2048 + m16) * 2048) + 1024 + h * 64 + quad * 8;
  // V frag (ds,ts) at vb + ds*16*2048 + t0 + ts*16
  const u16* vb = vtg + ((size_t)(b * 16 + h) * 64 + m16) * 2048 + quad * 4;

  f32x4 oT[2][4] = {};
  f32x4 oL[2] = {};
  float mrun[2] = {-1e30f, -1e30f};

  f16x4 ones;
#pragma unroll
  for (int j = 0; j < 4; ++j) ones[j] = (_Float16)1.0f;

  bf16x8 kA[4][2], kB[4][2];
  f16x4 vf[4][4];

  auto loadK = [&](bf16x8(&KF)[4][2], int T0) {
#pragma unroll
    for (int ts = 0; ts < 4; ++ts) {
      KF[ts][0] = *(const bf16x8*)&kb[(size_t)(T0 + ts * 16) * 2048];
      KF[ts][1] = *(const bf16x8*)&kb[(size_t)(T0 + ts * 16) * 2048 + 32];
    }
  };
  auto loadV = [&](int T0) {
#pragma unroll
    for (int ds = 0; ds < 4; ++ds)
#pragma unroll
      for (int ts = 0; ts < 4; ++ts)
        vf[ds][ts] = *(const f16x4*)&vb[(size_t)ds * 32768 + T0 + ts * 16];
  };
  auto body = [&](const bf16x8(&KF)[4][2], int T0) {
    // ---- S^T = K Q^T : rows key, cols q ----
    f32x4 sv[2][4];
#pragma unroll
    for (int ts = 0; ts < 4; ++ts)
#pragma unroll
      for (int qs = 0; qs < 2; ++qs) {
        f32x4 a = {};
        a = MFMA16(KF[ts][0], qa[qs][0], a);
        a = MFMA16(KF[ts][1], qa[qs][1], a);
        sv[qs][ts] = a;
      }
    // ---- causal mask (straddling iters only) ----
    if (T0 + 63 > wq0) {
#pragma unroll
      for (int qs = 0; qs < 2; ++qs)
#pragma unroll
        for (int ts = 0; ts < 4; ++ts)
#pragma unroll
          for (int rr = 0; rr < 4; ++rr) {
            int key = T0 + ts * 16 + quad * 4 + rr;
            if (key > wq0 + qs * 16 + m16) sv[qs][ts][rr] = -3e38f;
          }
    }
    // ---- softmax: exact per-row max (2 shfls), exp2, pack; l via MFMA ----
    f16x4 pf[2][4];
#pragma unroll
    for (int qs = 0; qs < 2; ++qs) {
      float mx = fmaxf(fmaxf(sv[qs][0][0], sv[qs][0][1]),
                       fmaxf(sv[qs][0][2], sv[qs][0][3]));
#pragma unroll
      for (int ts = 1; ts < 4; ++ts)
        mx = fmaxf(mx, fmaxf(fmaxf(sv[qs][ts][0], sv[qs][ts][1]),
                             fmaxf(sv[qs][ts][2], sv[qs][ts][3])));
      mx = fmaxf(mx, __shfl_xor(mx, 16));
      mx = fmaxf(mx, __shfl_xor(mx, 32));
      float mnew = fmaxf(mrun[qs], mx);
      float alpha = exp2f(mrun[qs] - mnew);
      mrun[qs] = mnew;
      oL[qs] *= alpha;
#pragma unroll
      for (int ds = 0; ds < 4; ++ds) oT[qs][ds] *= alpha;
#pragma unroll
      for (int ts = 0; ts < 4; ++ts) {
        float p0 = exp2f(sv[qs][ts][0] - mnew);
        float p1 = exp2f(sv[qs][ts][1] - mnew);
        float p2 = exp2f(sv[qs][ts][2] - mnew);
        float p3 = exp2f(sv[qs][ts][3] - mnew);
        pf[qs][ts] = pack4h(p0, p1, p2, p3);
        oL[qs] = MFMAH(ones, pf[qs][ts], oL[qs]);
      }
    }
    // ---- O^T += V^T P^T ----
#pragma unroll
    for (int ts = 0; ts < 4; ++ts)
#pragma unroll
      for (int ds = 0; ds < 4; ++ds) {
        oT[0][ds] = MFMAH(vf[ds][ts], pf[0][ts], oT[0][ds]);
        oT[1][ds] = MFMAH(vf[ds][ts], pf[1][ts], oT[1][ds]);
      }
  };

  loadK(kA, k_start);
  int it = 0, t0 = k_start;
  while (true) {
    if (it + 1 < iters) loadK(kB, t0 + 64);
    loadV(t0);
    body(kA, t0);
    ++it;
    t0 += 64;
    if (it >= iters) break;
    if (it + 1 < iters) loadK(kA, t0 + 64);
    loadV(t0);
    body(kB, t0);
    ++it;
    t0 += 64;
    if (it >= iters) break;
  }

  if (st == 255) {
    // direct: normalize + store bf16 (l sits replicated in oL[qs][*])
#pragma unroll
    for (int qs = 0; qs < 2; ++qs) {
      float rl = 1.0f / oL[qs][0];
      int q = wq0 + qs * 16 + m16;
#pragma unroll
      for (int ds = 0; ds < 4; ++ds) {
        f32x4 o = oT[qs][ds];
        u32x2 ov = {(u32)f2b(o[0] * rl) | ((u32)f2b(o[1] * rl) << 16),
                    (u32)f2b(o[2] * rl) | ((u32)f2b(o[3] * rl) << 16)};
        *(u32x2*)&attn_out[(size_t)(b * 2048 + q) * 1024 + h * 64 + ds * 16 +
                           quad * 4] = ov;
      }
    }
  } else {
    // partial: unnormalized O^T f16 + (m, l)
    size_t sbase = ((size_t)st * 32 + bh) * 128;
#pragma unroll
    for (int qs = 0; qs < 2; ++qs) {
      int qloc = w * 32 + qs * 16 + m16;
#pragma unroll
      for (int ds = 0; ds < 4; ++ds) {
        f32x4 o = oT[qs][ds];
        u32x2 ov = {pkrtz(o[0], o[1]), pkrtz(o[2], o[3])};
        *(u32x2*)&opart[(sbase + qloc) * 64 + ds * 16 + quad * 4] = ov;
      }
      if (quad == 0) ml[sbase + qloc] = make_float2(mrun[qs], oL[qs][0]);
    }
  }
}

// Combine for qb>=8: grid (8, 32) = (qb-8, bh).
__global__ __launch_bounds__(256) void attn_comb(const u16* __restrict__ opart,
                                                 const float2* __restrict__ ml,
                                                 u16* __restrict__ attn_out) {
  int qb = 8 + blockIdx.x, bh = blockIdx.y;
  int b = bh >> 4, h = bh & 15;
  int nseg = (qb < 12) ? 2 : 4;
  int base = CB_BASE[qb - 8];
  int t = threadIdx.x;
  int q = t >> 1, dh = (t & 1) * 32;

  float m[4], l[4], wgt[4];
  float M = -3e38f;
  for (int s = 0; s < nseg; ++s) {
    float2 v = ml[((size_t)(base + s) * 32 + bh) * 128 + q];
    m[s] = v.x;
    l[s] = v.y;
    M = fmaxf(M, v.x);
  }
  float lsum = 0.0f;
  for (int s = 0; s < nseg; ++s) {
    wgt[s] = exp2f(m[s] - M);
    lsum += wgt[s] * l[s];
  }
  float rl = 1.0f / lsum;

  size_t orow = (size_t)(b * 2048 + qb * 128 + q) * 1024 + h * 64 + dh;
#pragma unroll 2
  for (int dd = 0; dd < 32; dd += 4) {
    float o0 = 0, o1 = 0, o2 = 0, o3 = 0;
    for (int s = 0; s < nseg; ++s) {
      f16x4 hv = __builtin_bit_cast(
          f16x4, *(const u32x2*)&opart[(((size_t)(base + s) * 32 + bh) * 128 + q) * 64 +
                                       dh + dd]);
      o0 += wgt[s] * (float)hv[0];
      o1 += wgt[s] * (float)hv[1];
      o2 += wgt[s] * (float)hv[2];
      o3 += wgt[s] * (float)hv[3];
    }
    u32x2 ov = {(u32)f2b(o0 * rl) | ((u32)f2b(o1 * rl) << 16),
                (u32)f2b(o2 * rl) | ((u32)f2b(o3 * rl) << 16)};
    *(u32x2*)&attn_out[orow + dd] = ov;
  }
}

// ---------------------------------------------------------------- combine + layernorm

__global__ __launch_bounds__(256) void ln_comb(const u16* __restrict__ parts, int np,
                                               const float* __restrict__ bias,
                                               const float* __restrict__ resid,
                                               const float* __restrict__ g,
                                               const float* __restrict__ be,
                                               float* __restrict__ outF,
                                               u16* __restrict__ outB) {
  int row = blockIdx.x;
  int t = threadIdx.x;
  size_t off = (size_t)row * 1024 + t * 4;
  float4 bv4 = *(const float4*)(bias + t * 4);
  float a0 = bv4.x, a1 = bv4.y, a2 = bv4.z, a3 = bv4.w;
  for (int c = 0; c < np; ++c) {
    f16x4 hv =
        __builtin_bit_cast(f16x4, *(const u32x2*)&parts[(size_t)c * 4096 * 1024 + off]);
    a0 += (float)hv[0];
    a1 += (float)hv[1];
    a2 += (float)hv[2];
    a3 += (float)hv[3];
  }
  float4 rv = *(const float4*)(resid + off);
  a0 += rv.x;
  a1 += rv.y;
  a2 += rv.z;
  a3 += rv.w;

  float s = a0 + a1 + a2 + a3;
  float sq = a0 * a0 + a1 * a1 + a2 * a2 + a3 * a3;
#pragma unroll
  for (int d = 1; d < 64; d <<= 1) {
    s += __shfl_xor(s, d);
    sq += __shfl_xor(sq, d);
  }
  __shared__ float red[8];
  int lane = t & 63, wid = t >> 6;
  if (lane == 0) {
    red[wid] = s;
    red[4 + wid] = sq;
  }
  __syncthreads();
  s = red[0] + red[1] + red[2] + red[3];
  sq = red[4] + red[5] + red[6] + red[7];
  float mu = s * (1.0f / 1024.0f);
  float var = sq * (1.0f / 1024.0f) - mu * mu;
  float rstd = rsqrtf(var + 1e-5f);
  float4 gv = *(const float4*)(g + t * 4);
  float4 bev = *(const float4*)(be + t * 4);
  float o0 = (a0 - mu) * rstd * gv.x + bev.x;
  float o1 = (a1 - mu) * rstd * gv.y + bev.y;
  float o2 = (a2 - mu) * rstd * gv.z + bev.z;
  float o3 = (a3 - mu) * rstd * gv.w + bev.w;
  if (outF) {
    float4 ov = {o0, o1, o2, o3};
    *(float4*)(outF + off) = ov;
  }
  if (outB) {
    outB[off + 0] = f2b(o0);
    outB[off + 1] = f2b(o1);
    outB[off + 2] = f2b(o2);
    outB[off + 3] = f2b(o3);
  }
}

// ---------------------------------------------------------------- launch

extern "C" void kernel_launch(void* const* d_in, const int* in_sizes, int n_in,
                              void* d_out, int out_size, void* d_ws, size_t ws_size,
                              hipStream_t stream) {
  const float* x = (const float*)d_in[0];
  const float* wq = (const float*)d_in[1];
  const float* wk = (const float*)d_in[2];
  const float* wv = (const float*)d_in[3];
  const float* w_proj = (const float*)d_in[4];
  const float* b_proj = (const float*)d_in[5];
  const float* w1 = (const float*)d_in[6];
  const float* b1 = (const float*)d_in[7];
  const float* w2 = (const float*)d_in[8];
  const float* b2 = (const float*)d_in[9];
  const float* g1 = (const float*)d_in[10];
  const float* be1 = (const float*)d_in[11];
  const float* g2 = (const float*)d_in[12];
  const float* be2 = (const float*)d_in[13];
  float* out = (float*)d_out;

  const int M = 4096;  // B*S
  char* w = (char*)d_ws;
  u16* Xbf = (u16*)w;        w += (size_t)M * 1024 * 2;           // [0,8)
  u16* WqkvT = (u16*)w;      w += (size_t)3072 * 1024 * 2;        // [8,14)
  u16* WprojT = (u16*)w;     w += (size_t)1024 * 1024 * 2;        // [14,16)
  u16* W1T = (u16*)w;        w += (size_t)4096 * 1024 * 2;        // [16,24)
  u16* X1b = (u16*)w;        w += (size_t)M * 1024 * 2;           // [24,32)
  u16* W2T = (u16*)w;        w += (size_t)1024 * 4096 * 2;        // [32,40)
  u16* QK = (u16*)w;         w += (size_t)M * 2048 * 2;           // [40,56)
  u16* Vtg = (u16*)w;        w += (size_t)2 * 16 * 64 * 2048 * 2; // [56,64)
  u16* Attn = (u16*)w;       w += (size_t)M * 1024 * 2;           // [64,72)
  float* X1f = (float*)w;    w += (size_t)M * 1024 * 4;           // [72,88)

  u16* Pdown = Xbf;   // 4 x 8 MB f16 partials over dead [0,32)
  u16* Pproj = QK;    // 2 x 8 MB f16 partials over dead [40,56)
  u16* Hbuf = QK;     // 32 MB bf16 H over dead [40,72)
  u16* Opart = (u16*)X1f;                                  // 12.6 MB over dead X1f
  float2* Ml = (float2*)((char*)X1f + (size_t)13 * 1024 * 1024);  // 0.79 MB

  // 1. pack
  castx_kernel<<<M * 1024 / 1024, 256, 0, stream>>>(x, Xbf);
  tcast_qkv_kernel<<<dim3(2, 32, 48), dim3(32, 8), 0, stream>>>(wq, wk, wv, WqkvT);
  tcast_kernel<<<dim3(32, 32), dim3(32, 8), 0, stream>>>(w_proj, WprojT, 1024, 1024);
  tcast_kernel<<<dim3(128, 32), dim3(32, 8), 0, stream>>>(w1, W1T, 1024, 4096);
  tcast_kernel<<<dim3(32, 128), dim3(32, 8), 0, stream>>>(w2, W2T, 4096, 1024);

  // 2. QKV: Q,K natural bf16 (ldc=2048) + V transposed f16. grid (32,24)
  gemm_bf16<3><<<dim3(32, 24, 1), 256, 0, stream>>>(Xbf, WqkvT, M, 3072, 1024, 1024,
                                                    nullptr, QK, 2048, Vtg);

  // 3. attention: 1024 LPT blocks (direct qb<8; split-K qb>=8) + combine
  attn_part<<<1024, 256, 0, stream>>>(QK, Vtg, Attn, Opart, Ml);
  attn_comb<<<dim3(8, 32), 256, 0, stream>>>(Opart, Ml, Attn);

  // 4. proj split-K KS=2 -> f16 partials; LN1 combines (+b_proj +x)
  gemm_bf16<4><<<dim3(32, 8, 2), 256, 0, stream>>>(Attn, WprojT, M, 1024, 512, 1024,
                                                   nullptr, Pproj, 1024, nullptr);
  ln_comb<<<M, 256, 0, stream>>>(Pproj, 2, b_proj, x, g1, be1, X1f, X1b);

  // 5. MLP up: relu bf16 -> Hbuf. grid (32,32)
  gemm_bf16<1><<<dim3(32, 32, 1), 256, 0, stream>>>(X1b, W1T, M, 4096, 1024, 1024, b1,
                                                    Hbuf, 4096, nullptr);

  // 6. MLP down split-K KS=4 -> f16 partials; LN2 combines (+b2 +X1f) -> d_out
  gemm_bf16<4><<<dim3(32, 8, 4), 256, 0, stream>>>(Hbuf, W2T, M, 1024, 1024, 4096,
                                                   nullptr, Pdown, 1024, nullptr);
  ln_comb<<<M, 256, 0, stream>>>(Pdown, 4, b2, X1f, g2, be2, out, nullptr);
}

// Round 10
// 316.964 us; speedup vs baseline: 1.2885x; 1.2885x over previous
//
#include <hip/hip_runtime.h>

// Transformer block on MI355X. bf16 MFMA for GEMMs/QK^T, fp16 MFMA for PV, fp32 stats.
// GEMM: C[M,N] = A[M,K] (row-major bf16) x Bt[N,K] (row-major bf16 = B^T).
// MFMA 16x16x32 bf16 frags: A/B [idx=lane&15][k=quad*8+j]; C/D col=lane&15, row=quad*4+reg.
// MFMA 16x16x16 f16 frags:  A/B [idx=lane&15][k=quad*4+j]; C/D same 16x16 layout.
// Grid-swap: blockIdx.x = M-tile so all blocks sharing an A-strip land on one XCD.
// Split-K GEMMs write f16 partials; ln_comb sums partials + bias + residual + LN.
// Attention v7 (best found): LDS + async DMA staging, double-buffered, one
// barrier/iter; split-K only for qb>=8. v8 (barrier-free streaming) regressed.

typedef unsigned short u16;
typedef unsigned int u32;
typedef __attribute__((ext_vector_type(8))) short bf16x8;
typedef __attribute__((ext_vector_type(4))) float f32x4;
typedef __attribute__((ext_vector_type(2))) u32 u32x2;
typedef __attribute__((ext_vector_type(4))) _Float16 f16x4;

#define MFMA16(a, b, c) __builtin_amdgcn_mfma_f32_16x16x32_bf16(a, b, c, 0, 0, 0)
#define MFMAH(a, b, c) __builtin_amdgcn_mfma_f32_16x16x16f16(a, b, c, 0, 0, 0)

__device__ __forceinline__ u16 f2b(float f) {
  unsigned int u = __builtin_bit_cast(unsigned int, f);
  u = (u + 0x7fffu + ((u >> 16) & 1u)) >> 16;
  return (u16)u;
}

__device__ __forceinline__ void gload_lds16(const u16* g, u16* l) {
  __builtin_amdgcn_global_load_lds((const __attribute__((address_space(1))) void*)g,
                                   (__attribute__((address_space(3))) void*)l, 16, 0, 0);
}

__device__ __forceinline__ u32 pkrtz(float lo, float hi) {
  return __builtin_bit_cast(u32, __builtin_amdgcn_cvt_pkrtz(lo, hi));
}

__device__ __forceinline__ f16x4 pack4h(float a, float b, float c, float d) {
  u32x2 r = {pkrtz(a, b), pkrtz(c, d)};
  return __builtin_bit_cast(f16x4, r);
}

__device__ __forceinline__ u16 f2h(float v) {
  return __builtin_bit_cast(u16, (_Float16)v);
}

// ---------------------------------------------------------------- uber pack
// One launch: qkv head-transposes (3072 blocks), proj (1024), w1 (4096),
// w2 (4096), then x cast (4096). 16384 blocks x 256 threads.

__global__ __launch_bounds__(256) void pack_all(
    const float* __restrict__ x, const float* __restrict__ wq,
    const float* __restrict__ wk, const float* __restrict__ wv,
    const float* __restrict__ wp, const float* __restrict__ w1,
    const float* __restrict__ w2, u16* __restrict__ Xbf, u16* __restrict__ WqkvT,
    u16* __restrict__ WprojT, u16* __restrict__ W1T, u16* __restrict__ W2T) {
  int bid = blockIdx.x;
  int t = threadIdx.x;
  if (bid >= 12288) {  // x cast segment: 4096 blocks x 1024 elems
    size_t i = ((size_t)(bid - 12288) * 256 + t) * 4;
    float4 v = *(const float4*)(x + i);
    Xbf[i + 0] = f2b(v.x);
    Xbf[i + 1] = f2b(v.y);
    Xbf[i + 2] = f2b(v.z);
    Xbf[i + 3] = f2b(v.w);
    return;
  }
  __shared__ float tile[32][33];
  int tx = t & 31, ty = t >> 5;
  const float* src;
  u16* dst;
  int R, C, r0, c0;
  float scale = 1.0f;
  if (bid < 3072) {  // qkv: per-(proj,head) [1024 d][64 k] -> [k][d]
    int z = bid >> 6, q = bid & 63;
    int p = z >> 4, h = z & 15;
    src = (p == 0 ? wq : (p == 1 ? wk : wv)) + (size_t)h * 1024 * 64;
    scale = (p == 0) ? 0.1803368801f : 1.0f;  // 0.125 * log2(e)
    dst = WqkvT + (size_t)(p * 1024 + h * 64) * 1024;
    R = 1024; C = 64;
    c0 = (q & 1) * 32; r0 = (q >> 1) * 32;
  } else if (bid < 4096) {
    int q = bid - 3072;
    src = wp; dst = WprojT; R = 1024; C = 1024;
    c0 = (q & 31) * 32; r0 = (q >> 5) * 32;
  } else if (bid < 8192) {
    int q = bid - 4096;
    src = w1; dst = W1T; R = 1024; C = 4096;
    c0 = (q & 127) * 32; r0 = (q >> 7) * 32;
  } else {
    int q = bid - 8192;
    src = w2; dst = W2T; R = 4096; C = 1024;
    c0 = (q & 31) * 32; r0 = (q >> 5) * 32;
  }
#pragma unroll
  for (int i = 0; i < 4; ++i)
    tile[ty + i * 8][tx] = src[(size_t)(r0 + ty + i * 8) * C + c0 + tx];
  __syncthreads();
#pragma unroll
  for (int i = 0; i < 4; ++i)
    dst[(size_t)(c0 + ty + i * 8) * R + r0 + tx] = f2b(tile[tx][ty + i * 8] * scale);
}

// ---------------------------------------------------------------- GEMM v3
// BM=128, BN=128, BK=64, grid (Mtiles, Ntiles, KS). k range [z*Kc, (z+1)*Kc).
// LDS staged via global_load_lds with 16B-chunk XOR swizzle (conflict-free reads).
// __launch_bounds__(256,4): cap VGPR<=128 -> 4 blocks/CU (was 3 at ~132 VGPR).
// MODE 1: relu(C+bias) bf16 -> outB (ldc)
// MODE 3: QKV fused: n0<2048 -> bf16 natural (ldc) | n0>=2048 -> V^T f16 to vtg
// MODE 4: f16 partial -> outB + z*M*N (combined later by ln_comb)

template <int MODE>
__global__ __launch_bounds__(256, 4) void gemm_bf16(const u16* __restrict__ A,
                                                    const u16* __restrict__ Bt, int M,
                                                    int N, int Kc, int lda,
                                                    const float* __restrict__ bias,
                                                    u16* __restrict__ outB, int ldc,
                                                    u16* __restrict__ vtg) {
  constexpr int BM = 128, BN = 128, BK = 64;
  constexpr int IM = 4, JN = 4;
  __shared__ u16 As[BM * BK];
  __shared__ u16 Bs[BN * BK];
  int t = threadIdx.x;
  int m0 = blockIdx.x * BM, n0 = blockIdx.y * BN;
  int kb = blockIdx.z * Kc;
  int lane = t & 63, wid = t >> 6;
  int wm = (wid >> 1) * 64, wn = (wid & 1) * 64;
  int m16 = lane & 15, quad = lane >> 4;
  int sw = m16 & 7;

  f32x4 acc[IM][JN] = {};

  for (int k0 = kb; k0 < kb + Kc; k0 += BK) {
    __syncthreads();
#pragma unroll
    for (int i = 0; i < 4; ++i) {
      int S = i * 256 + t;
      int row = S >> 3, c = S & 7;
      gload_lds16(&A[(size_t)(m0 + row) * lda + k0 + (c ^ (row & 7)) * 8],
                  &As[(i * 256 + wid * 64) * 8]);
    }
#pragma unroll
    for (int i = 0; i < 4; ++i) {
      int S = i * 256 + t;
      int row = S >> 3, c = S & 7;
      gload_lds16(&Bt[(size_t)(n0 + row) * lda + k0 + (c ^ (row & 7)) * 8],
                  &Bs[(i * 256 + wid * 64) * 8]);
    }
    __syncthreads();
#pragma unroll
    for (int kk = 0; kk < 2; ++kk) {
      bf16x8 af[IM], bfr[JN];
      int slot = (kk * 4 + quad) ^ sw;
#pragma unroll
      for (int i = 0; i < IM; ++i)
        af[i] = *(const bf16x8*)&As[(wm + i * 16 + m16) * BK + slot * 8];
#pragma unroll
      for (int j = 0; j < JN; ++j)
        bfr[j] = *(const bf16x8*)&Bs[(wn + j * 16 + m16) * BK + slot * 8];
#pragma unroll
      for (int i = 0; i < IM; ++i)
#pragma unroll
        for (int j = 0; j < JN; ++j) acc[i][j] = MFMA16(af[i], bfr[j], acc[i][j]);
    }
  }

  if (MODE == 3 && n0 >= 2048) {
#pragma unroll
    for (int i = 0; i < IM; ++i)
#pragma unroll
      for (int j = 0; j < JN; ++j) {
        int dg = n0 + wn + j * 16 + m16 - 2048;
        int hh = dg >> 6, dd = dg & 63;
        int token = m0 + wm + i * 16 + quad * 4;
        int bb = token >> 11, tt = token & 2047;
        u32x2 pv = {pkrtz(acc[i][j][0], acc[i][j][1]),
                    pkrtz(acc[i][j][2], acc[i][j][3])};
        *(u32x2*)&vtg[(((size_t)bb * 16 + hh) * 64 + dd) * 2048 + tt] = pv;
      }
    return;
  }

  u16* pb = (MODE == 4) ? outB + (size_t)blockIdx.z * M * N : outB;
#pragma unroll
  for (int i = 0; i < IM; ++i)
#pragma unroll
    for (int j = 0; j < JN; ++j) {
      int col = n0 + wn + j * 16 + m16;
      float bv = (MODE == 1) ? bias[col] : 0.0f;
#pragma unroll
      for (int r = 0; r < 4; ++r) {
        int row = m0 + wm + i * 16 + quad * 4 + r;
        float v = acc[i][j][r];
        if (MODE == 1) {
          v += bv;
          v = v > 0.0f ? v : 0.0f;
          pb[(size_t)row * ldc + col] = f2b(v);
        } else if (MODE == 4) {
          pb[(size_t)row * ldc + col] = f2h(v);
        } else {
          pb[(size_t)row * ldc + col] = f2b(v);
        }
      }
    }
}

// ---------------------------------------------------------------- attention v7
// qb<8 (<=1024 keys): single block, direct normalized write.
// qb 8-11: 2 segments; qb 12-15: 4 segments -> f16 partials + (m,l), combined
// by attn_comb. 32 slots x 32 bh = 1024 blocks, LPT-ordered (longest first).

__constant__ unsigned char R_QB[32] = {7, 6, 11, 11, 5, 10, 10, 9, 9, 4, 8,
                                       8, 3, 15, 15, 15, 15, 14, 14, 14, 13, 13,
                                       13, 13, 12, 12, 12, 2, 14, 12, 1, 0};
__constant__ unsigned char R_K0[32] = {0, 0, 0, 12, 0, 0, 11, 0, 10, 0, 0,
                                       9, 0, 0, 8, 16, 24, 0, 8, 16, 0, 7,
                                       14, 21, 0, 7, 14, 0, 24, 21, 0, 0};
__constant__ unsigned char R_NIT[32] = {16, 14, 12, 12, 12, 11, 11, 10, 10, 10, 9,
                                        9, 8, 8, 8, 8, 8, 8, 8, 8, 7, 7,
                                        7, 7, 7, 7, 7, 6, 6, 5, 4, 2};
__constant__ unsigned char R_ST[32] = {255, 255, 6, 7, 255, 4, 5, 2, 3, 255, 0,
                                       1, 255, 20, 21, 22, 23, 16, 17, 18, 12, 13,
                                       14, 15, 8, 9, 10, 255, 19, 11, 255, 255};
__constant__ unsigned char CB_BASE[8] = {0, 2, 4, 6, 8, 12, 16, 20};

__global__ __launch_bounds__(256) void attn_part(const u16* __restrict__ qk,
                                                 const u16* __restrict__ vtg,
                                                 u16* __restrict__ attn_out,
                                                 u16* __restrict__ opart,
                                                 float2* __restrict__ ml) {
  int rank = blockIdx.x >> 5, bh = blockIdx.x & 31;
  int qb = R_QB[rank];
  int k_start = R_K0[rank] * 64;
  int iters = R_NIT[rank];
  int st = R_ST[rank];
  int b = bh >> 4, h = bh & 15;

  int t = threadIdx.x, lane = t & 63, w = t >> 6;
  int m16 = lane & 15, quad = lane >> 4;
  int wq0 = qb * 128 + w * 32;

  __shared__ u16 Ks[2][64 * 64];  // [key][d] bf16, chunk-swizzled
  __shared__ u16 Vs[2][64 * 64];  // [d][key] f16, chunk-swizzled

  bf16x8 qa[2][2];
#pragma unroll
  for (int qs = 0; qs < 2; ++qs) {
    const u16* qp = qk + (size_t)(b * 2048 + wq0 + qs * 16 + m16) * 2048 + h * 64;
    qa[qs][0] = *(const bf16x8*)&qp[quad * 8];
    qa[qs][1] = *(const bf16x8*)&qp[32 + quad * 8];
  }

  f32x4 oT[2][4] = {};
  f32x4 lacc[2] = {};
  float mrun[2] = {-1e30f, -1e30f};

  int row0 = t >> 3, c0 = t & 7;
  int row1 = 32 + row0;
  const u16* kbase = qk + (size_t)(b * 2048) * 2048 + 1024 + h * 64;
  const u16* vbase = vtg + ((size_t)(b * 16 + h) * 64) * 2048;
  int sw = m16 & 7;

#define STAGE_ASYNC(T0, BUF)                                                        \
  {                                                                                 \
    gload_lds16(&kbase[(size_t)((T0) + row0) * 2048 + (c0 ^ (row0 & 7)) * 8],       \
                &Ks[BUF][(w * 64) * 8]);                                            \
    gload_lds16(&kbase[(size_t)((T0) + row1) * 2048 + (c0 ^ (row1 & 7)) * 8],       \
                &Ks[BUF][(256 + w * 64) * 8]);                                      \
    gload_lds16(&vbase[(size_t)row0 * 2048 + (T0) + (c0 ^ (row0 & 7)) * 8],         \
                &Vs[BUF][(w * 64) * 8]);                                            \
    gload_lds16(&vbase[(size_t)row1 * 2048 + (T0) + (c0 ^ (row1 & 7)) * 8],         \
                &Vs[BUF][(256 + w * 64) * 8]);                                      \
  }

  STAGE_ASYNC(k_start, 0);
  __syncthreads();

  for (int it = 0; it < iters; ++it) {
    int t0 = k_start + it * 64;
    int cur = it & 1;
    if (it + 1 < iters) STAGE_ASYNC(t0 + 64, !cur);

    if (t0 <= wq0 + 31) {
      f32x4 sv[2][4];
#pragma unroll
      for (int ts = 0; ts < 4; ++ts) {
        bf16x8 ka0 = *(const bf16x8*)&Ks[cur][(ts * 16 + m16) * 64 + (quad ^ sw) * 8];
        bf16x8 ka1 =
            *(const bf16x8*)&Ks[cur][(ts * 16 + m16) * 64 + ((4 + quad) ^ sw) * 8];
#pragma unroll
        for (int qs = 0; qs < 2; ++qs) {
          f32x4 a = {};
          a = MFMA16(ka0, qa[qs][0], a);
          a = MFMA16(ka1, qa[qs][1], a);
          sv[qs][ts] = a;
        }
      }
      if (t0 + 63 > wq0) {
#pragma unroll
        for (int qs = 0; qs < 2; ++qs)
#pragma unroll
          for (int ts = 0; ts < 4; ++ts)
#pragma unroll
            for (int rr = 0; rr < 4; ++rr) {
              int key = t0 + ts * 16 + quad * 4 + rr;
              if (key > wq0 + qs * 16 + m16) sv[qs][ts][rr] = -3e38f;
            }
      }
#pragma unroll
      for (int qs = 0; qs < 2; ++qs) {
        float mx = fmaxf(fmaxf(sv[qs][0][0], sv[qs][0][1]),
                         fmaxf(sv[qs][0][2], sv[qs][0][3]));
#pragma unroll
        for (int ts = 1; ts < 4; ++ts)
          mx = fmaxf(mx, fmaxf(fmaxf(sv[qs][ts][0], sv[qs][ts][1]),
                               fmaxf(sv[qs][ts][2], sv[qs][ts][3])));
        mx = fmaxf(mx, __shfl_xor(mx, 16));
        mx = fmaxf(mx, __shfl_xor(mx, 32));
        float mnew = fmaxf(mrun[qs], mx);
        float alpha = exp2f(mrun[qs] - mnew);
        mrun[qs] = mnew;
        lacc[qs] *= alpha;
#pragma unroll
        for (int ds = 0; ds < 4; ++ds) oT[qs][ds] *= alpha;
      }
      f16x4 pf[2][4];
#pragma unroll
      for (int qs = 0; qs < 2; ++qs)
#pragma unroll
        for (int ts = 0; ts < 4; ++ts) {
          float p0 = exp2f(sv[qs][ts][0] - mrun[qs]);
          float p1 = exp2f(sv[qs][ts][1] - mrun[qs]);
          float p2 = exp2f(sv[qs][ts][2] - mrun[qs]);
          float p3 = exp2f(sv[qs][ts][3] - mrun[qs]);
          lacc[qs][0] += p0;
          lacc[qs][1] += p1;
          lacc[qs][2] += p2;
          lacc[qs][3] += p3;
          pf[qs][ts] = pack4h(p0, p1, p2, p3);
        }
#pragma unroll
      for (int ts = 0; ts < 4; ++ts)
#pragma unroll
        for (int ds = 0; ds < 4; ++ds) {
          f16x4 av = __builtin_bit_cast(
              f16x4, *(const u32x2*)&Vs[cur][(ds * 16 + m16) * 64 +
                                             (((ts * 2 + (quad >> 1)) ^ sw) * 8) +
                                             (quad & 1) * 4]);
          oT[0][ds] = MFMAH(av, pf[0][ts], oT[0][ds]);
          oT[1][ds] = MFMAH(av, pf[1][ts], oT[1][ds]);
        }
    }
    __syncthreads();
  }
#undef STAGE_ASYNC

  if (st == 255) {
#pragma unroll
    for (int qs = 0; qs < 2; ++qs) {
      float ls = lacc[qs][0] + lacc[qs][1] + lacc[qs][2] + lacc[qs][3];
      ls += __shfl_xor(ls, 16);
      ls += __shfl_xor(ls, 32);
      float rl = 1.0f / ls;
      int q = wq0 + qs * 16 + m16;
#pragma unroll
      for (int ds = 0; ds < 4; ++ds) {
        f32x4 o = oT[qs][ds];
        u32x2 ov = {(u32)f2b(o[0] * rl) | ((u32)f2b(o[1] * rl) << 16),
                    (u32)f2b(o[2] * rl) | ((u32)f2b(o[3] * rl) << 16)};
        *(u32x2*)&attn_out[(size_t)(b * 2048 + q) * 1024 + h * 64 + ds * 16 +
                           quad * 4] = ov;
      }
    }
  } else {
    size_t sbase = ((size_t)st * 32 + bh) * 128;
#pragma unroll
    for (int qs = 0; qs < 2; ++qs) {
      float ls = lacc[qs][0] + lacc[qs][1] + lacc[qs][2] + lacc[qs][3];
      ls += __shfl_xor(ls, 16);
      ls += __shfl_xor(ls, 32);
      int qloc = w * 32 + qs * 16 + m16;
#pragma unroll
      for (int ds = 0; ds < 4; ++ds) {
        f32x4 o = oT[qs][ds];
        u32x2 ov = {pkrtz(o[0], o[1]), pkrtz(o[2], o[3])};
        *(u32x2*)&opart[(sbase + qloc) * 64 + ds * 16 + quad * 4] = ov;
      }
      if (quad == 0) ml[sbase + qloc] = make_float2(mrun[qs], ls);
    }
  }
}

// Combine for qb>=8: grid (8, 32) = (qb-8, bh).
__global__ __launch_bounds__(256) void attn_comb(const u16* __restrict__ opart,
                                                 const float2* __restrict__ ml,
                                                 u16* __restrict__ attn_out) {
  int qb = 8 + blockIdx.x, bh = blockIdx.y;
  int b = bh >> 4, h = bh & 15;
  int nseg = (qb < 12) ? 2 : 4;
  int base = CB_BASE[qb - 8];
  int t = threadIdx.x;
  int q = t >> 1, dh = (t & 1) * 32;

  float m[4], l[4], wgt[4];
  float M = -3e38f;
  for (int s = 0; s < nseg; ++s) {
    float2 v = ml[((size_t)(base + s) * 32 + bh) * 128 + q];
    m[s] = v.x;
    l[s] = v.y;
    M = fmaxf(M, v.x);
  }
  float lsum = 0.0f;
  for (int s = 0; s < nseg; ++s) {
    wgt[s] = exp2f(m[s] - M);
    lsum += wgt[s] * l[s];
  }
  float rl = 1.0f / lsum;

  size_t orow = (size_t)(b * 2048 + qb * 128 + q) * 1024 + h * 64 + dh;
#pragma unroll 2
  for (int dd = 0; dd < 32; dd += 4) {
    float o0 = 0, o1 = 0, o2 = 0, o3 = 0;
    for (int s = 0; s < nseg; ++s) {
      f16x4 hv = __builtin_bit_cast(
          f16x4, *(const u32x2*)&opart[(((size_t)(base + s) * 32 + bh) * 128 + q) * 64 +
                                       dh + dd]);
      o0 += wgt[s] * (float)hv[0];
      o1 += wgt[s] * (float)hv[1];
      o2 += wgt[s] * (float)hv[2];
      o3 += wgt[s] * (float)hv[3];
    }
    u32x2 ov = {(u32)f2b(o0 * rl) | ((u32)f2b(o1 * rl) << 16),
                (u32)f2b(o2 * rl) | ((u32)f2b(o3 * rl) << 16)};
    *(u32x2*)&attn_out[orow + dd] = ov;
  }
}

// ---------------------------------------------------------------- combine + layernorm

__global__ __launch_bounds__(256) void ln_comb(const u16* __restrict__ parts, int np,
                                               const float* __restrict__ bias,
                                               const float* __restrict__ resid,
                                               const float* __restrict__ g,
                                               const float* __restrict__ be,
                                               float* __restrict__ outF,
                                               u16* __restrict__ outB) {
  int row = blockIdx.x;
  int t = threadIdx.x;
  size_t off = (size_t)row * 1024 + t * 4;
  float4 bv4 = *(const float4*)(bias + t * 4);
  float a0 = bv4.x, a1 = bv4.y, a2 = bv4.z, a3 = bv4.w;
  for (int c = 0; c < np; ++c) {
    f16x4 hv =
        __builtin_bit_cast(f16x4, *(const u32x2*)&parts[(size_t)c * 4096 * 1024 + off]);
    a0 += (float)hv[0];
    a1 += (float)hv[1];
    a2 += (float)hv[2];
    a3 += (float)hv[3];
  }
  float4 rv = *(const float4*)(resid + off);
  a0 += rv.x;
  a1 += rv.y;
  a2 += rv.z;
  a3 += rv.w;

  float s = a0 + a1 + a2 + a3;
  float sq = a0 * a0 + a1 * a1 + a2 * a2 + a3 * a3;
#pragma unroll
  for (int d = 1; d < 64; d <<= 1) {
    s += __shfl_xor(s, d);
    sq += __shfl_xor(sq, d);
  }
  __shared__ float red[8];
  int lane = t & 63, wid = t >> 6;
  if (lane == 0) {
    red[wid] = s;
    red[4 + wid] = sq;
  }
  __syncthreads();
  s = red[0] + red[1] + red[2] + red[3];
  sq = red[4] + red[5] + red[6] + red[7];
  float mu = s * (1.0f / 1024.0f);
  float var = sq * (1.0f / 1024.0f) - mu * mu;
  float rstd = rsqrtf(var + 1e-5f);
  float4 gv = *(const float4*)(g + t * 4);
  float4 bev = *(const float4*)(be + t * 4);
  float o0 = (a0 - mu) * rstd * gv.x + bev.x;
  float o1 = (a1 - mu) * rstd * gv.y + bev.y;
  float o2 = (a2 - mu) * rstd * gv.z + bev.z;
  float o3 = (a3 - mu) * rstd * gv.w + bev.w;
  if (outF) {
    float4 ov = {o0, o1, o2, o3};
    *(float4*)(outF + off) = ov;
  }
  if (outB) {
    outB[off + 0] = f2b(o0);
    outB[off + 1] = f2b(o1);
    outB[off + 2] = f2b(o2);
    outB[off + 3] = f2b(o3);
  }
}

// ---------------------------------------------------------------- launch

extern "C" void kernel_launch(void* const* d_in, const int* in_sizes, int n_in,
                              void* d_out, int out_size, void* d_ws, size_t ws_size,
                              hipStream_t stream) {
  const float* x = (const float*)d_in[0];
  const float* wq = (const float*)d_in[1];
  const float* wk = (const float*)d_in[2];
  const float* wv = (const float*)d_in[3];
  const float* w_proj = (const float*)d_in[4];
  const float* b_proj = (const float*)d_in[5];
  const float* w1 = (const float*)d_in[6];
  const float* b1 = (const float*)d_in[7];
  const float* w2 = (const float*)d_in[8];
  const float* b2 = (const float*)d_in[9];
  const float* g1 = (const float*)d_in[10];
  const float* be1 = (const float*)d_in[11];
  const float* g2 = (const float*)d_in[12];
  const float* be2 = (const float*)d_in[13];
  float* out = (float*)d_out;

  const int M = 4096;  // B*S
  char* w = (char*)d_ws;
  u16* Xbf = (u16*)w;        w += (size_t)M * 1024 * 2;           // [0,8)
  u16* WqkvT = (u16*)w;      w += (size_t)3072 * 1024 * 2;        // [8,14)
  u16* WprojT = (u16*)w;     w += (size_t)1024 * 1024 * 2;        // [14,16)
  u16* W1T = (u16*)w;        w += (size_t)4096 * 1024 * 2;        // [16,24)
  u16* X1b = (u16*)w;        w += (size_t)M * 1024 * 2;           // [24,32)
  u16* W2T = (u16*)w;        w += (size_t)1024 * 4096 * 2;        // [32,40)
  u16* QK = (u16*)w;         w += (size_t)M * 2048 * 2;           // [40,56)
  u16* Vtg = (u16*)w;        w += (size_t)2 * 16 * 64 * 2048 * 2; // [56,64)
  u16* Attn = (u16*)w;       w += (size_t)M * 1024 * 2;           // [64,72)
  float* X1f = (float*)w;    w += (size_t)M * 1024 * 4;           // [72,88)

  u16* Pdown = Xbf;   // 4 x 8 MB f16 partials over dead [0,32)
  u16* Pproj = QK;    // 2 x 8 MB f16 partials over dead [40,56)
  u16* Hbuf = QK;     // 32 MB bf16 H over dead [40,72)
  u16* Opart = (u16*)X1f;                                  // 12.6 MB over dead X1f
  float2* Ml = (float2*)((char*)X1f + (size_t)13 * 1024 * 1024);  // 0.79 MB

  // 1. pack (one launch: qkv/proj/w1/w2 transposes + x cast)
  pack_all<<<16384, 256, 0, stream>>>(x, wq, wk, wv, w_proj, w1, w2, Xbf, WqkvT,
                                      WprojT, W1T, W2T);

  // 2. QKV: Q,K natural bf16 (ldc=2048) + V transposed f16. grid (32,24)
  gemm_bf16<3><<<dim3(32, 24, 1), 256, 0, stream>>>(Xbf, WqkvT, M, 3072, 1024, 1024,
                                                    nullptr, QK, 2048, Vtg);

  // 3. attention: 1024 LPT blocks (direct qb<8; split-K qb>=8) + combine
  attn_part<<<1024, 256, 0, stream>>>(QK, Vtg, Attn, Opart, Ml);
  attn_comb<<<dim3(8, 32), 256, 0, stream>>>(Opart, Ml, Attn);

  // 4. proj split-K KS=2 -> f16 partials; LN1 combines (+b_proj +x)
  gemm_bf16<4><<<dim3(32, 8, 2), 256, 0, stream>>>(Attn, WprojT, M, 1024, 512, 1024,
                                                   nullptr, Pproj, 1024, nullptr);
  ln_comb<<<M, 256, 0, stream>>>(Pproj, 2, b_proj, x, g1, be1, X1f, X1b);

  // 5. MLP up: relu bf16 -> Hbuf. grid (32,32)
  gemm_bf16<1><<<dim3(32, 32, 1), 256, 0, stream>>>(X1b, W1T, M, 4096, 1024, 1024, b1,
                                                    Hbuf, 4096, nullptr);

  // 6. MLP down split-K KS=4 -> f16 partials; LN2 combines (+b2 +X1f) -> d_out
  gemm_bf16<4><<<dim3(32, 8, 4), 256, 0, stream>>>(Hbuf, W2T, M, 1024, 1024, 4096,
                                                   nullptr, Pdown, 1024, nullptr);
  ln_comb<<<M, 256, 0, stream>>>(Pdown, 4, b2, X1f, g2, be2, out, nullptr);
}